// Round 1
// baseline (487.167 us; speedup 1.0000x reference)
//
#include <hip/hip_runtime.h>
#include <hip/hip_bf16.h>

typedef unsigned short u16;
typedef short s16x8 __attribute__((ext_vector_type(8)));
typedef float f32x4 __attribute__((ext_vector_type(4)));
typedef float f32x4e __attribute__((ext_vector_type(4)));
typedef u16 u16x4 __attribute__((ext_vector_type(4)));

#define D_MODEL 1024
#define NHEAD 16
#define DK 64
#define B_ 4
#define N_ 2048
#define M_TOT (B_ * N_) /* 8192 */
#define LDP 80          /* padded LDS row stride (elems) for attention tiles */

__device__ __forceinline__ u16 f2b(float x) {
  __hip_bfloat16 h = __float2bfloat16(x);
  return __builtin_bit_cast(u16, h);
}

__device__ __forceinline__ void gload_lds16(const void* gp, void* lp) {
  __builtin_amdgcn_global_load_lds(
      (const __attribute__((address_space(1))) unsigned int*)gp,
      (__attribute__((address_space(3))) unsigned int*)lp, 16, 0, 0);
}

// ---------------- elementwise f32 -> bf16 ----------------
__global__ __launch_bounds__(256) void cvt_f32_bf16(const float* __restrict__ x,
                                                    u16* __restrict__ y, int n4) {
  int i = blockIdx.x * 256 + threadIdx.x;
  if (i < n4) {
    f32x4e v = *(const f32x4e*)(x + (size_t)i * 4);
    u16x4 o;
    o[0] = f2b(v[0]); o[1] = f2b(v[1]); o[2] = f2b(v[2]); o[3] = f2b(v[3]);
    *(u16x4*)(y + (size_t)i * 4) = o;
  }
}

// ---------------- W (f32, [K][N]) -> W^T (bf16, [N][K]) ----------------
__global__ __launch_bounds__(256) void wtrans(const float* __restrict__ W,
                                              u16* __restrict__ Wt) {
  __shared__ float tile[32][33];
  int bi = blockIdx.y, bj = blockIdx.x;
  int tx = threadIdx.x & 31, ty = threadIdx.x >> 5; // 32 x 8
#pragma unroll
  for (int r = 0; r < 4; ++r)
    tile[ty + r * 8][tx] = W[(size_t)(bi * 32 + ty + r * 8) * D_MODEL + bj * 32 + tx];
  __syncthreads();
#pragma unroll
  for (int r = 0; r < 4; ++r)
    Wt[(size_t)(bj * 32 + ty + r * 8) * D_MODEL + bi * 32 + tx] = f2b(tile[tx][ty + r * 8]);
}

// ------------- V [B,N,H*64] bf16 -> Vt [B,H,64,N] bf16 -------------
__global__ __launch_bounds__(256) void vtrans(const u16* __restrict__ Vp,
                                              u16* __restrict__ Vt) {
  __shared__ u16 tile[64][65];
  int n0 = blockIdx.x * 64, h = blockIdx.y, b = blockIdx.z;
  int tx = threadIdx.x & 63, ty = threadIdx.x >> 6;
  for (int r = ty; r < 64; r += 4)
    tile[r][tx] = Vp[(size_t)(b * N_ + n0 + r) * D_MODEL + h * DK + tx];
  __syncthreads();
  for (int r = ty; r < 64; r += 4)
    Vt[((size_t)(b * NHEAD + h) * DK + r) * N_ + n0 + tx] = tile[tx][r];
}

// ------------- GEMM: C[M,N] = A[M,K](bf16) * Bt[N,K](bf16)^T -------------
// m97 structure: 128x128 tile, BK=32, 4 waves each 64x64, global_load_lds w=16.
template <bool OUT_F32>
__global__ __launch_bounds__(256) void gemm_bt(const u16* __restrict__ A,
                                               const u16* __restrict__ Bt,
                                               float* __restrict__ Cf,
                                               u16* __restrict__ Cb,
                                               int M, int N, int K) {
  __shared__ __align__(16) u16 Atile[128 * 32];
  __shared__ __align__(16) u16 Btile[128 * 32];
  int tid = threadIdx.x;
  int w = tid >> 6, lane = tid & 63;
  int g = lane >> 4, c = lane & 15;
  int wr = w >> 1, wc = w & 1;
  int bi = blockIdx.y, bj = blockIdx.x;
  const int rowA0 = bi * 128, rowB0 = bj * 128;

  const f32x4 fzero = {0.f, 0.f, 0.f, 0.f};
  f32x4 acc[4][4];
#pragma unroll
  for (int m = 0; m < 4; ++m)
#pragma unroll
    for (int n = 0; n < 4; ++n) acc[m][n] = fzero;

  for (int k0 = 0; k0 < K; k0 += 32) {
#pragma unroll
    for (int cc = 0; cc < 2; ++cc) {
      int li = w * 2 + cc;
      const u16* ga = A + (size_t)(rowA0 + li * 16 + (lane >> 2)) * K + k0 + (lane & 3) * 8;
      gload_lds16(ga, &Atile[li * 512]);
      const u16* gb = Bt + (size_t)(rowB0 + li * 16 + (lane >> 2)) * K + k0 + (lane & 3) * 8;
      gload_lds16(gb, &Btile[li * 512]);
    }
    __syncthreads();
    s16x8 af[4], bfr[4];
#pragma unroll
    for (int m = 0; m < 4; ++m)
      af[m] = *(const s16x8*)&Atile[(wr * 64 + m * 16 + c) * 32 + g * 8];
#pragma unroll
    for (int n = 0; n < 4; ++n)
      bfr[n] = *(const s16x8*)&Btile[(wc * 64 + n * 16 + c) * 32 + g * 8];
#pragma unroll
    for (int m = 0; m < 4; ++m)
#pragma unroll
      for (int n = 0; n < 4; ++n)
        acc[m][n] = __builtin_amdgcn_mfma_f32_16x16x32_bf16(af[m], bfr[n], acc[m][n], 0, 0, 0);
    __syncthreads();
  }
  // epilogue: C/D layout col=lane&15, row=(lane>>4)*4+reg
#pragma unroll
  for (int m = 0; m < 4; ++m)
#pragma unroll
    for (int n = 0; n < 4; ++n)
#pragma unroll
      for (int r = 0; r < 4; ++r) {
        int row = rowA0 + wr * 64 + m * 16 + g * 4 + r;
        int col = rowB0 + wc * 64 + n * 16 + c;
        size_t idx = (size_t)row * N + col;
        if (OUT_F32) Cf[idx] = acc[m][n][r];
        else Cb[idx] = f2b(acc[m][n][r]);
      }
}

// ------------- causal flash attention, bf16 MFMA -------------
// grid: (qtile=32, h=16, b=4), 256 threads = 4 waves, each wave 16 q-rows.
__global__ __launch_bounds__(256) void attn_fwd(const u16* __restrict__ Qp,
                                                const u16* __restrict__ Kp,
                                                const u16* __restrict__ Vt,
                                                const int* __restrict__ mask,
                                                u16* __restrict__ Out) {
  __shared__ __align__(16) u16 Klds[64 * LDP]; // [kv][d] padded
  __shared__ __align__(16) u16 Vlds[64 * LDP]; // [d][kv] padded
  __shared__ __align__(16) u16 Plds[4][16 * LDP];
  int qt = blockIdx.x, h = blockIdx.y, b = blockIdx.z;
  int tid = threadIdx.x, w = tid >> 6, lane = tid & 63;
  int g = lane >> 4, c = lane & 15;
  int q0 = qt * 64;

  const u16* qbase = Qp + (size_t)(b * N_ + q0 + w * 16 + c) * D_MODEL + h * DK;
  s16x8 qf0 = *(const s16x8*)(qbase + g * 8);
  s16x8 qf1 = *(const s16x8*)(qbase + 32 + g * 8);

  const f32x4 fzero = {0.f, 0.f, 0.f, 0.f};
  f32x4 oacc[4];
#pragma unroll
  for (int d = 0; d < 4; ++d) oacc[d] = fzero;
  float mr[4], lr[4];
#pragma unroll
  for (int r = 0; r < 4; ++r) { mr[r] = -INFINITY; lr[r] = 0.f; }

  const u16* kbase = Kp + (size_t)b * N_ * D_MODEL + h * DK;
  const u16* vbase = Vt + (size_t)(b * NHEAD + h) * DK * N_;

  for (int t = 0; t <= qt; ++t) {
    int kv0 = t * 64;
    // stage K (row=kv, 64 bf16 each) and V^T (row=d, 64 kv each) into padded LDS
#pragma unroll
    for (int cc = 0; cc < 2; ++cc) {
      int idx = cc * 256 + tid;
      int kr = idx >> 3, kc = (idx & 7) * 8;
      *(s16x8*)&Klds[kr * LDP + kc] =
          *(const s16x8*)(kbase + (size_t)(kv0 + kr) * D_MODEL + kc);
      *(s16x8*)&Vlds[kr * LDP + kc] =
          *(const s16x8*)(vbase + (size_t)kr * N_ + kv0 + kc);
    }
    __syncthreads();

    // S = Q K^T  (16 q x 64 kv per wave)
    f32x4 s[4];
#pragma unroll
    for (int n = 0; n < 4; ++n) {
      s[n] = fzero;
      s16x8 kf0 = *(const s16x8*)&Klds[(n * 16 + c) * LDP + g * 8];
      s16x8 kf1 = *(const s16x8*)&Klds[(n * 16 + c) * LDP + 32 + g * 8];
      s[n] = __builtin_amdgcn_mfma_f32_16x16x32_bf16(qf0, kf0, s[n], 0, 0, 0);
      s[n] = __builtin_amdgcn_mfma_f32_16x16x32_bf16(qf1, kf1, s[n], 0, 0, 0);
    }

    // scale + masks + online softmax (row stats across 16-lane group)
    float p[4][4];
    float tmax[4] = {-INFINITY, -INFINITY, -INFINITY, -INFINITY};
#pragma unroll
    for (int n = 0; n < 4; ++n) {
      int kv = kv0 + n * 16 + c;
      int pm = mask[b * N_ + kv];
#pragma unroll
      for (int r = 0; r < 4; ++r) {
        float vv = s[n][r] * 0.125f;
        int qq = q0 + w * 16 + g * 4 + r;
        if (pm == 0 || kv > qq) vv = -INFINITY;
        p[n][r] = vv;
        tmax[r] = fmaxf(tmax[r], vv);
      }
    }
#pragma unroll
    for (int r = 0; r < 4; ++r) {
      tmax[r] = fmaxf(tmax[r], __shfl_xor(tmax[r], 1));
      tmax[r] = fmaxf(tmax[r], __shfl_xor(tmax[r], 2));
      tmax[r] = fmaxf(tmax[r], __shfl_xor(tmax[r], 4));
      tmax[r] = fmaxf(tmax[r], __shfl_xor(tmax[r], 8));
    }
    float alpha[4];
#pragma unroll
    for (int r = 0; r < 4; ++r) {
      float mnew = fmaxf(mr[r], tmax[r]);
      alpha[r] = (mnew == -INFINITY) ? 1.f : expf(mr[r] - mnew);
      mr[r] = mnew;
    }
#pragma unroll
    for (int n = 0; n < 4; ++n)
#pragma unroll
      for (int r = 0; r < 4; ++r)
        p[n][r] = (p[n][r] == -INFINITY) ? 0.f : expf(p[n][r] - mr[r]);
#pragma unroll
    for (int r = 0; r < 4; ++r) {
      float rs = p[0][r] + p[1][r] + p[2][r] + p[3][r];
      rs += __shfl_xor(rs, 1);
      rs += __shfl_xor(rs, 2);
      rs += __shfl_xor(rs, 4);
      rs += __shfl_xor(rs, 8);
      lr[r] = lr[r] * alpha[r] + rs;
    }
#pragma unroll
    for (int d = 0; d < 4; ++d)
#pragma unroll
      for (int r = 0; r < 4; ++r) oacc[d][r] *= alpha[r];

    // P -> per-wave padded LDS (re-layout into MFMA A-operand form)
#pragma unroll
    for (int n = 0; n < 4; ++n)
#pragma unroll
      for (int r = 0; r < 4; ++r)
        Plds[w][(g * 4 + r) * LDP + n * 16 + c] = f2b(p[n][r]);
    asm volatile("s_waitcnt lgkmcnt(0)" ::: "memory");

    // O += P * V
#pragma unroll
    for (int ks = 0; ks < 2; ++ks) {
      s16x8 pf = *(const s16x8*)&Plds[w][c * LDP + ks * 32 + g * 8];
#pragma unroll
      for (int d = 0; d < 4; ++d) {
        s16x8 vf = *(const s16x8*)&Vlds[(d * 16 + c) * LDP + ks * 32 + g * 8];
        oacc[d] = __builtin_amdgcn_mfma_f32_16x16x32_bf16(pf, vf, oacc[d], 0, 0, 0);
      }
    }
    __syncthreads();
  }

  // normalize + store bf16 [B,N,H*64]
#pragma unroll
  for (int r = 0; r < 4; ++r) {
    float inv = lr[r] > 0.f ? 1.f / lr[r] : 0.f;
#pragma unroll
    for (int d = 0; d < 4; ++d) {
      size_t idx = (size_t)(b * N_ + q0 + w * 16 + g * 4 + r) * D_MODEL + h * DK + d * 16 + c;
      Out[idx] = f2b(oacc[d][r] * inv);
    }
  }
}

extern "C" void kernel_launch(void* const* d_in, const int* in_sizes, int n_in,
                              void* d_out, int out_size, void* d_ws, size_t ws_size,
                              hipStream_t stream) {
  const float* q = (const float*)d_in[0];
  const float* k = (const float*)d_in[1];
  const float* v = (const float*)d_in[2];
  const int* mask = (const int*)d_in[3];
  const float* Wq = (const float*)d_in[4];
  const float* Wk = (const float*)d_in[5];
  const float* Wv = (const float*)d_in[6];
  const float* Wo = (const float*)d_in[7];
  float* out = (float*)d_out;

  char* ws = (char*)d_ws;
  const size_t SZ = (size_t)M_TOT * D_MODEL * 2; // 16 MiB per bf16 [8192,1024]
  u16* qb = (u16*)ws;
  u16* kb = (u16*)(ws + SZ);
  u16* vb = (u16*)(ws + 2 * SZ);
  u16* Qp = (u16*)(ws + 3 * SZ);
  u16* Kp = (u16*)(ws + 4 * SZ);
  u16* Wqt = (u16*)(ws + 5 * SZ);
  u16* Wkt = Wqt + 1024 * 1024;
  u16* Wvt = Wkt + 1024 * 1024;
  u16* Wot = Wvt + 1024 * 1024;
  // aliases (lifetime-disjoint):
  u16* attn_out = qb; // qb dead after Q GEMM
  u16* Vp = kb;       // kb dead after K GEMM
  u16* Vt = vb;       // vb dead after V GEMM

  int n4 = M_TOT * D_MODEL / 4;
  cvt_f32_bf16<<<n4 / 256, 256, 0, stream>>>(q, qb, n4);
  cvt_f32_bf16<<<n4 / 256, 256, 0, stream>>>(k, kb, n4);
  cvt_f32_bf16<<<n4 / 256, 256, 0, stream>>>(v, vb, n4);
  dim3 wg(32, 32);
  wtrans<<<wg, 256, 0, stream>>>(Wq, Wqt);
  wtrans<<<wg, 256, 0, stream>>>(Wk, Wkt);
  wtrans<<<wg, 256, 0, stream>>>(Wv, Wvt);
  wtrans<<<wg, 256, 0, stream>>>(Wo, Wot);
  dim3 gg(D_MODEL / 128, M_TOT / 128);
  gemm_bt<false><<<gg, 256, 0, stream>>>(qb, Wqt, nullptr, Qp, M_TOT, D_MODEL, D_MODEL);
  gemm_bt<false><<<gg, 256, 0, stream>>>(kb, Wkt, nullptr, Kp, M_TOT, D_MODEL, D_MODEL);
  gemm_bt<false><<<gg, 256, 0, stream>>>(vb, Wvt, nullptr, Vp, M_TOT, D_MODEL, D_MODEL);
  vtrans<<<dim3(N_ / 64, NHEAD, B_), 256, 0, stream>>>(Vp, Vt);
  attn_fwd<<<dim3(N_ / 64, NHEAD, B_), 256, 0, stream>>>(Qp, Kp, Vt, mask, attn_out);
  gemm_bt<true><<<gg, 256, 0, stream>>>(attn_out, Wot, out, nullptr, M_TOT, D_MODEL, D_MODEL);
}

// Round 2
// 435.932 us; speedup vs baseline: 1.1175x; 1.1175x over previous
//
#include <hip/hip_runtime.h>
#include <hip/hip_bf16.h>

typedef unsigned short u16;
typedef short s16x8 __attribute__((ext_vector_type(8)));
typedef float f32x4 __attribute__((ext_vector_type(4)));
typedef u16 u16x4 __attribute__((ext_vector_type(4)));

#define D_MODEL 1024
#define NHEAD 16
#define DK 64
#define B_ 4
#define N_ 2048
#define M_TOT (B_ * N_) /* 8192 */
#define QBLK 128
#define KVBLK 64
#define LDP 72 /* padded LDS row stride: 144B = 36 banks -> conflict-free b128 */
#define SCALE2 0.1803368801111137f /* 0.125 * log2(e) */

__device__ __forceinline__ u16 f2b(float x) {
  __hip_bfloat16 h = __float2bfloat16(x);
  return __builtin_bit_cast(u16, h);
}

__device__ __forceinline__ void gload_lds16(const void* gp, void* lp) {
  __builtin_amdgcn_global_load_lds(
      (const __attribute__((address_space(1))) unsigned int*)gp,
      (__attribute__((address_space(3))) unsigned int*)lp, 16, 0, 0);
}

// ---------------- elementwise f32 -> bf16 ----------------
__global__ __launch_bounds__(256) void cvt_f32_bf16(const float* __restrict__ x,
                                                    u16* __restrict__ y, int n4) {
  int i = blockIdx.x * 256 + threadIdx.x;
  if (i < n4) {
    f32x4 v = *(const f32x4*)(x + (size_t)i * 4);
    u16x4 o;
    o[0] = f2b(v[0]); o[1] = f2b(v[1]); o[2] = f2b(v[2]); o[3] = f2b(v[3]);
    *(u16x4*)(y + (size_t)i * 4) = o;
  }
}

// ---------------- padding mask -> float bias (0 or -inf) ----------------
__global__ __launch_bounds__(256) void mask_bias(const int* __restrict__ mask,
                                                 float* __restrict__ Mb, int n) {
  int i = blockIdx.x * 256 + threadIdx.x;
  if (i < n) Mb[i] = mask[i] ? 0.f : -INFINITY;
}

// ---------------- W (f32, [K][N]) -> W^T (bf16, [N][K]) ----------------
__global__ __launch_bounds__(256) void wtrans(const float* __restrict__ W,
                                              u16* __restrict__ Wt) {
  __shared__ float tile[32][33];
  int bi = blockIdx.y, bj = blockIdx.x;
  int tx = threadIdx.x & 31, ty = threadIdx.x >> 5; // 32 x 8
#pragma unroll
  for (int r = 0; r < 4; ++r)
    tile[ty + r * 8][tx] = W[(size_t)(bi * 32 + ty + r * 8) * D_MODEL + bj * 32 + tx];
  __syncthreads();
#pragma unroll
  for (int r = 0; r < 4; ++r)
    Wt[(size_t)(bj * 32 + ty + r * 8) * D_MODEL + bi * 32 + tx] = f2b(tile[tx][ty + r * 8]);
}

// ------------- V [B,N,H*64] bf16 -> Vt [B,H,64,N] bf16 -------------
__global__ __launch_bounds__(256) void vtrans(const u16* __restrict__ Vp,
                                              u16* __restrict__ Vt) {
  __shared__ u16 tile[64][65];
  int n0 = blockIdx.x * 64, h = blockIdx.y, b = blockIdx.z;
  int tx = threadIdx.x & 63, ty = threadIdx.x >> 6;
  for (int r = ty; r < 64; r += 4)
    tile[r][tx] = Vp[(size_t)(b * N_ + n0 + r) * D_MODEL + h * DK + tx];
  __syncthreads();
  for (int r = ty; r < 64; r += 4)
    Vt[((size_t)(b * NHEAD + h) * DK + r) * N_ + n0 + tx] = tile[tx][r];
}

// ------------- GEMM: C[M,N] = A[M,K](bf16) * Bt[N,K](bf16)^T -------------
template <bool OUT_F32>
__global__ __launch_bounds__(256) void gemm_bt(const u16* __restrict__ A,
                                               const u16* __restrict__ Bt,
                                               float* __restrict__ Cf,
                                               u16* __restrict__ Cb,
                                               int M, int N, int K) {
  __shared__ __align__(16) u16 Atile[128 * 32];
  __shared__ __align__(16) u16 Btile[128 * 32];
  int tid = threadIdx.x;
  int w = tid >> 6, lane = tid & 63;
  int g = lane >> 4, c = lane & 15;
  int wr = w >> 1, wc = w & 1;
  int bi = blockIdx.y, bj = blockIdx.x;
  const int rowA0 = bi * 128, rowB0 = bj * 128;

  const f32x4 fzero = {0.f, 0.f, 0.f, 0.f};
  f32x4 acc[4][4];
#pragma unroll
  for (int m = 0; m < 4; ++m)
#pragma unroll
    for (int n = 0; n < 4; ++n) acc[m][n] = fzero;

  for (int k0 = 0; k0 < K; k0 += 32) {
#pragma unroll
    for (int cc = 0; cc < 2; ++cc) {
      int li = w * 2 + cc;
      const u16* ga = A + (size_t)(rowA0 + li * 16 + (lane >> 2)) * K + k0 + (lane & 3) * 8;
      gload_lds16(ga, &Atile[li * 512]);
      const u16* gb = Bt + (size_t)(rowB0 + li * 16 + (lane >> 2)) * K + k0 + (lane & 3) * 8;
      gload_lds16(gb, &Btile[li * 512]);
    }
    __syncthreads();
    s16x8 af[4], bfr[4];
#pragma unroll
    for (int m = 0; m < 4; ++m)
      af[m] = *(const s16x8*)&Atile[(wr * 64 + m * 16 + c) * 32 + g * 8];
#pragma unroll
    for (int n = 0; n < 4; ++n)
      bfr[n] = *(const s16x8*)&Btile[(wc * 64 + n * 16 + c) * 32 + g * 8];
#pragma unroll
    for (int m = 0; m < 4; ++m)
#pragma unroll
      for (int n = 0; n < 4; ++n)
        acc[m][n] = __builtin_amdgcn_mfma_f32_16x16x32_bf16(af[m], bfr[n], acc[m][n], 0, 0, 0);
    __syncthreads();
  }
#pragma unroll
  for (int m = 0; m < 4; ++m)
#pragma unroll
    for (int n = 0; n < 4; ++n)
#pragma unroll
      for (int r = 0; r < 4; ++r) {
        int row = rowA0 + wr * 64 + m * 16 + g * 4 + r;
        int col = rowB0 + wc * 64 + n * 16 + c;
        size_t idx = (size_t)row * N + col;
        if (OUT_F32) Cf[idx] = acc[m][n][r];
        else Cb[idx] = f2b(acc[m][n][r]);
      }
}

// ------------- causal flash attention, bf16 MFMA, QBLK=128 -------------
// grid: (16 qtiles, 16 h, 4 b), 256 threads = 4 waves, each wave 32 q-rows.
__global__ __launch_bounds__(256) void attn_fwd(const u16* __restrict__ Qp,
                                                const u16* __restrict__ Kp,
                                                const u16* __restrict__ Vt,
                                                const float* __restrict__ Mb,
                                                u16* __restrict__ Out) {
  __shared__ __align__(16) u16 Klds[KVBLK * LDP]; // [kv][d] padded
  __shared__ __align__(16) u16 Vlds[DK * LDP];    // [d][kv] padded
  __shared__ __align__(16) u16 Plds[4][32 * LDP]; // per-wave P [qrow][kv]
  int qt = (N_ / QBLK - 1) - blockIdx.x; // heavy tiles first
  int h = blockIdx.y, b = blockIdx.z;
  int tid = threadIdx.x, w = tid >> 6, lane = tid & 63;
  int g = lane >> 4, c = lane & 15;
  int q0 = qt * QBLK;
  int wq0 = q0 + w * 32; // this wave's first q row

  // Q fragments: rows wq0 + m*16 + c, k = kh*32 + g*8
  s16x8 qf[2][2];
#pragma unroll
  for (int m = 0; m < 2; ++m) {
    const u16* qb2 = Qp + (size_t)(b * N_ + wq0 + m * 16 + c) * D_MODEL + h * DK;
#pragma unroll
    for (int kh = 0; kh < 2; ++kh) qf[m][kh] = *(const s16x8*)(qb2 + kh * 32 + g * 8);
  }

  const f32x4 fzero = {0.f, 0.f, 0.f, 0.f};
  f32x4 oacc[2][4];
#pragma unroll
  for (int m = 0; m < 2; ++m)
#pragma unroll
    for (int d = 0; d < 4; ++d) oacc[m][d] = fzero;
  float mr[2][4], lr[2][4];
#pragma unroll
  for (int m = 0; m < 2; ++m)
#pragma unroll
    for (int r = 0; r < 4; ++r) { mr[m][r] = -1e30f; lr[m][r] = 0.f; }

  const u16* kbase = Kp + (size_t)b * N_ * D_MODEL + h * DK;
  const u16* vbase = Vt + (size_t)(b * NHEAD + h) * DK * N_;
  const float* mbase = Mb + (size_t)b * N_;

  int nt = 2 * qt + 2; // k-tiles covering rows <= q0+127
  for (int t = 0; t < nt; ++t) {
    int kv0 = t * KVBLK;
    // stage K[kv][d] and V^T[d][kv] into padded LDS (reg-staged, vectorized)
#pragma unroll
    for (int cc = 0; cc < 2; ++cc) {
      int idx = cc * 256 + tid;
      int kr = idx >> 3, kc = (idx & 7) * 8;
      *(s16x8*)&Klds[kr * LDP + kc] =
          *(const s16x8*)(kbase + (size_t)(kv0 + kr) * D_MODEL + kc);
      *(s16x8*)&Vlds[kr * LDP + kc] =
          *(const s16x8*)(vbase + (size_t)kr * N_ + kv0 + kc);
    }
    __syncthreads();

    if (kv0 <= wq0 + 31) { // wave has at least one unmasked row
      // ---- S = Q K^T : 2m x 4n frags
      f32x4 s[2][4];
#pragma unroll
      for (int n = 0; n < 4; ++n) {
        s16x8 kf0 = *(const s16x8*)&Klds[(n * 16 + c) * LDP + g * 8];
        s16x8 kf1 = *(const s16x8*)&Klds[(n * 16 + c) * LDP + 32 + g * 8];
#pragma unroll
        for (int m = 0; m < 2; ++m) {
          f32x4 acc = fzero;
          acc = __builtin_amdgcn_mfma_f32_16x16x32_bf16(qf[m][0], kf0, acc, 0, 0, 0);
          acc = __builtin_amdgcn_mfma_f32_16x16x32_bf16(qf[m][1], kf1, acc, 0, 0, 0);
          s[m][n] = acc;
        }
      }

      // ---- scale into exp2 domain + padding bias + (diagonal-only) causal
      float mb[4];
#pragma unroll
      for (int n = 0; n < 4; ++n) mb[n] = mbase[kv0 + n * 16 + c];
      bool diag = (kv0 + KVBLK - 1 > wq0);
      float tmax[2][4];
#pragma unroll
      for (int m = 0; m < 2; ++m)
#pragma unroll
        for (int r = 0; r < 4; ++r) tmax[m][r] = -INFINITY;
#pragma unroll
      for (int m = 0; m < 2; ++m)
#pragma unroll
        for (int n = 0; n < 4; ++n) {
          int kv = kv0 + n * 16 + c;
#pragma unroll
          for (int r = 0; r < 4; ++r) {
            float vv = fmaf(s[m][n][r], SCALE2, mb[n]);
            if (diag) {
              int qq = wq0 + m * 16 + g * 4 + r;
              vv = (kv > qq) ? -INFINITY : vv;
            }
            s[m][n][r] = vv;
            tmax[m][r] = fmaxf(tmax[m][r], vv);
          }
        }
      // row max across the 16-lane group
#pragma unroll
      for (int m = 0; m < 2; ++m)
#pragma unroll
        for (int r = 0; r < 4; ++r) {
          float v = tmax[m][r];
          v = fmaxf(v, __shfl_xor(v, 1));
          v = fmaxf(v, __shfl_xor(v, 2));
          v = fmaxf(v, __shfl_xor(v, 4));
          v = fmaxf(v, __shfl_xor(v, 8));
          tmax[m][r] = v;
        }
      float alpha[2][4];
#pragma unroll
      for (int m = 0; m < 2; ++m)
#pragma unroll
        for (int r = 0; r < 4; ++r) {
          float mnew = fmaxf(mr[m][r], tmax[m][r]);
          alpha[m][r] = exp2f(mr[m][r] - mnew);
          mr[m][r] = mnew;
        }
      // p = exp2(s - m); exp2(-inf - m) = 0 handles both masks for free
#pragma unroll
      for (int m = 0; m < 2; ++m)
#pragma unroll
        for (int n = 0; n < 4; ++n)
#pragma unroll
          for (int r = 0; r < 4; ++r)
            s[m][n][r] = exp2f(s[m][n][r] - mr[m][r]);
      // row sum + state update
#pragma unroll
      for (int m = 0; m < 2; ++m)
#pragma unroll
        for (int r = 0; r < 4; ++r) {
          float rs = s[m][0][r] + s[m][1][r] + s[m][2][r] + s[m][3][r];
          rs += __shfl_xor(rs, 1);
          rs += __shfl_xor(rs, 2);
          rs += __shfl_xor(rs, 4);
          rs += __shfl_xor(rs, 8);
          lr[m][r] = lr[m][r] * alpha[m][r] + rs;
        }
#pragma unroll
      for (int m = 0; m < 2; ++m)
#pragma unroll
        for (int d = 0; d < 4; ++d)
#pragma unroll
          for (int r = 0; r < 4; ++r) oacc[m][d][r] *= alpha[m][r];

      // ---- P -> per-wave LDS (A-operand re-layout)
#pragma unroll
      for (int m = 0; m < 2; ++m)
#pragma unroll
        for (int n = 0; n < 4; ++n)
#pragma unroll
          for (int r = 0; r < 4; ++r)
            Plds[w][(m * 16 + g * 4 + r) * LDP + n * 16 + c] = f2b(s[m][n][r]);
      asm volatile("s_waitcnt lgkmcnt(0)" ::: "memory");

      // ---- O += P * V
#pragma unroll
      for (int ks = 0; ks < 2; ++ks) {
        s16x8 vf[4];
#pragma unroll
        for (int d = 0; d < 4; ++d)
          vf[d] = *(const s16x8*)&Vlds[(d * 16 + c) * LDP + ks * 32 + g * 8];
#pragma unroll
        for (int m = 0; m < 2; ++m) {
          s16x8 pf = *(const s16x8*)&Plds[w][(m * 16 + c) * LDP + ks * 32 + g * 8];
#pragma unroll
          for (int d = 0; d < 4; ++d)
            oacc[m][d] = __builtin_amdgcn_mfma_f32_16x16x32_bf16(pf, vf[d], oacc[m][d], 0, 0, 0);
        }
      }
    }
    __syncthreads();
  }

  // normalize + store bf16 [B,N,H*64]
#pragma unroll
  for (int m = 0; m < 2; ++m)
#pragma unroll
    for (int r = 0; r < 4; ++r) {
      float inv = lr[m][r] > 0.f ? 1.f / lr[m][r] : 0.f;
#pragma unroll
      for (int d = 0; d < 4; ++d) {
        size_t idx = (size_t)(b * N_ + wq0 + m * 16 + g * 4 + r) * D_MODEL + h * DK + d * 16 + c;
        Out[idx] = f2b(oacc[m][d][r] * inv);
      }
    }
}

extern "C" void kernel_launch(void* const* d_in, const int* in_sizes, int n_in,
                              void* d_out, int out_size, void* d_ws, size_t ws_size,
                              hipStream_t stream) {
  const float* q = (const float*)d_in[0];
  const float* k = (const float*)d_in[1];
  const float* v = (const float*)d_in[2];
  const int* mask = (const int*)d_in[3];
  const float* Wq = (const float*)d_in[4];
  const float* Wk = (const float*)d_in[5];
  const float* Wv = (const float*)d_in[6];
  const float* Wo = (const float*)d_in[7];
  float* out = (float*)d_out;

  char* ws = (char*)d_ws;
  const size_t SZ = (size_t)M_TOT * D_MODEL * 2; // 16 MiB per bf16 [8192,1024]
  u16* qb = (u16*)ws;
  u16* kb = (u16*)(ws + SZ);
  u16* vb = (u16*)(ws + 2 * SZ);
  u16* Qp = (u16*)(ws + 3 * SZ);
  u16* Kp = (u16*)(ws + 4 * SZ);
  u16* Wqt = (u16*)(ws + 5 * SZ);
  u16* Wkt = Wqt + 1024 * 1024;
  u16* Wvt = Wkt + 1024 * 1024;
  u16* Wot = Wvt + 1024 * 1024;
  float* Mb = (float*)(Wot + 1024 * 1024);
  // aliases (lifetime-disjoint):
  u16* attn_out = qb; // qb dead after Q GEMM
  u16* Vp = kb;       // kb dead after K GEMM
  u16* Vt = vb;       // vb dead after V GEMM

  int n4 = M_TOT * D_MODEL / 4;
  cvt_f32_bf16<<<n4 / 256, 256, 0, stream>>>(q, qb, n4);
  cvt_f32_bf16<<<n4 / 256, 256, 0, stream>>>(k, kb, n4);
  cvt_f32_bf16<<<n4 / 256, 256, 0, stream>>>(v, vb, n4);
  mask_bias<<<(B_ * N_ + 255) / 256, 256, 0, stream>>>(mask, Mb, B_ * N_);
  dim3 wg(32, 32);
  wtrans<<<wg, 256, 0, stream>>>(Wq, Wqt);
  wtrans<<<wg, 256, 0, stream>>>(Wk, Wkt);
  wtrans<<<wg, 256, 0, stream>>>(Wv, Wvt);
  wtrans<<<wg, 256, 0, stream>>>(Wo, Wot);
  dim3 gg(D_MODEL / 128, M_TOT / 128);
  gemm_bt<false><<<gg, 256, 0, stream>>>(qb, Wqt, nullptr, Qp, M_TOT, D_MODEL, D_MODEL);
  gemm_bt<false><<<gg, 256, 0, stream>>>(kb, Wkt, nullptr, Kp, M_TOT, D_MODEL, D_MODEL);
  gemm_bt<false><<<gg, 256, 0, stream>>>(vb, Wvt, nullptr, Vp, M_TOT, D_MODEL, D_MODEL);
  vtrans<<<dim3(N_ / 64, NHEAD, B_), 256, 0, stream>>>(Vp, Vt);
  attn_fwd<<<dim3(N_ / QBLK, NHEAD, B_), 256, 0, stream>>>(Qp, Kp, Vt, Mb, attn_out);
  gemm_bt<true><<<gg, 256, 0, stream>>>(attn_out, Wot, out, nullptr, M_TOT, D_MODEL, D_MODEL);
}

// Round 3
// 368.533 us; speedup vs baseline: 1.3219x; 1.1829x over previous
//
#include <hip/hip_runtime.h>
#include <hip/hip_bf16.h>

typedef unsigned short u16;
typedef unsigned int u32;
typedef short s16x8 __attribute__((ext_vector_type(8)));
typedef float f32x4 __attribute__((ext_vector_type(4)));
typedef u16 u16x4 __attribute__((ext_vector_type(4)));
typedef u32 u32x2 __attribute__((ext_vector_type(2)));

#define D_MODEL 1024
#define NHEAD 16
#define DK 64
#define B_ 4
#define N_ 2048
#define M_TOT (B_ * N_) /* 8192 */
#define QBLK 128
#define KVBLK 64
#define SCALE2 0.1803368801111137f /* 0.125 * log2(e) */

__device__ __forceinline__ u16 f2b(float x) {
  __hip_bfloat16 h = __float2bfloat16(x);
  return __builtin_bit_cast(u16, h);
}

__device__ __forceinline__ void gload_lds16(const void* gp, void* lp) {
  __builtin_amdgcn_global_load_lds(
      (const __attribute__((address_space(1))) unsigned int*)gp,
      (__attribute__((address_space(3))) unsigned int*)lp, 16, 0, 0);
}

// ---------------- elementwise f32 -> bf16 ----------------
__global__ __launch_bounds__(256) void cvt_f32_bf16(const float* __restrict__ x,
                                                    u16* __restrict__ y, int n4) {
  int i = blockIdx.x * 256 + threadIdx.x;
  if (i < n4) {
    f32x4 v = *(const f32x4*)(x + (size_t)i * 4);
    u16x4 o;
    o[0] = f2b(v[0]); o[1] = f2b(v[1]); o[2] = f2b(v[2]); o[3] = f2b(v[3]);
    *(u16x4*)(y + (size_t)i * 4) = o;
  }
}

// ---------------- padding mask -> float bias (0 or -inf) ----------------
__global__ __launch_bounds__(256) void mask_bias(const int* __restrict__ mask,
                                                 float* __restrict__ Mb, int n) {
  int i = blockIdx.x * 256 + threadIdx.x;
  if (i < n) Mb[i] = mask[i] ? 0.f : -INFINITY;
}

// ---------------- W (f32, [K][N]) -> W^T (bf16, [N][K]) ----------------
__global__ __launch_bounds__(256) void wtrans(const float* __restrict__ W,
                                              u16* __restrict__ Wt) {
  __shared__ float tile[32][33];
  int bi = blockIdx.y, bj = blockIdx.x;
  int tx = threadIdx.x & 31, ty = threadIdx.x >> 5; // 32 x 8
#pragma unroll
  for (int r = 0; r < 4; ++r)
    tile[ty + r * 8][tx] = W[(size_t)(bi * 32 + ty + r * 8) * D_MODEL + bj * 32 + tx];
  __syncthreads();
#pragma unroll
  for (int r = 0; r < 4; ++r)
    Wt[(size_t)(bj * 32 + ty + r * 8) * D_MODEL + bi * 32 + tx] = f2b(tile[tx][ty + r * 8]);
}

// ------------- V [B,N,H*64] bf16 -> Vt [B,H,64,N] bf16 -------------
__global__ __launch_bounds__(256) void vtrans(const u16* __restrict__ Vp,
                                              u16* __restrict__ Vt) {
  __shared__ u16 tile[64][65];
  int n0 = blockIdx.x * 64, h = blockIdx.y, b = blockIdx.z;
  int tx = threadIdx.x & 63, ty = threadIdx.x >> 6;
  for (int r = ty; r < 64; r += 4)
    tile[r][tx] = Vp[(size_t)(b * N_ + n0 + r) * D_MODEL + h * DK + tx];
  __syncthreads();
  for (int r = ty; r < 64; r += 4)
    Vt[((size_t)(b * NHEAD + h) * DK + r) * N_ + n0 + tx] = tile[tx][r];
}

// ------------- GEMM: C[M,N] = A[M,K](bf16) * Bt[N,K](bf16)^T -------------
template <bool OUT_F32>
__global__ __launch_bounds__(256) void gemm_bt(const u16* __restrict__ A,
                                               const u16* __restrict__ Bt,
                                               float* __restrict__ Cf,
                                               u16* __restrict__ Cb,
                                               int M, int N, int K) {
  __shared__ __align__(16) u16 Atile[128 * 32];
  __shared__ __align__(16) u16 Btile[128 * 32];
  int tid = threadIdx.x;
  int w = tid >> 6, lane = tid & 63;
  int g = lane >> 4, c = lane & 15;
  int wr = w >> 1, wc = w & 1;
  int bi = blockIdx.y, bj = blockIdx.x;
  const int rowA0 = bi * 128, rowB0 = bj * 128;

  const f32x4 fzero = {0.f, 0.f, 0.f, 0.f};
  f32x4 acc[4][4];
#pragma unroll
  for (int m = 0; m < 4; ++m)
#pragma unroll
    for (int n = 0; n < 4; ++n) acc[m][n] = fzero;

  for (int k0 = 0; k0 < K; k0 += 32) {
#pragma unroll
    for (int cc = 0; cc < 2; ++cc) {
      int li = w * 2 + cc;
      const u16* ga = A + (size_t)(rowA0 + li * 16 + (lane >> 2)) * K + k0 + (lane & 3) * 8;
      gload_lds16(ga, &Atile[li * 512]);
      const u16* gb = Bt + (size_t)(rowB0 + li * 16 + (lane >> 2)) * K + k0 + (lane & 3) * 8;
      gload_lds16(gb, &Btile[li * 512]);
    }
    __syncthreads();
    s16x8 af[4], bfr[4];
#pragma unroll
    for (int m = 0; m < 4; ++m)
      af[m] = *(const s16x8*)&Atile[(wr * 64 + m * 16 + c) * 32 + g * 8];
#pragma unroll
    for (int n = 0; n < 4; ++n)
      bfr[n] = *(const s16x8*)&Btile[(wc * 64 + n * 16 + c) * 32 + g * 8];
#pragma unroll
    for (int m = 0; m < 4; ++m)
#pragma unroll
      for (int n = 0; n < 4; ++n)
        acc[m][n] = __builtin_amdgcn_mfma_f32_16x16x32_bf16(af[m], bfr[n], acc[m][n], 0, 0, 0);
    __syncthreads();
  }
#pragma unroll
  for (int m = 0; m < 4; ++m)
#pragma unroll
    for (int n = 0; n < 4; ++n)
#pragma unroll
      for (int r = 0; r < 4; ++r) {
        int row = rowA0 + wr * 64 + m * 16 + g * 4 + r;
        int col = rowB0 + wc * 64 + n * 16 + c;
        size_t idx = (size_t)row * N + col;
        if (OUT_F32) Cf[idx] = acc[m][n][r];
        else Cb[idx] = f2b(acc[m][n][r]);
      }
}

// ------------- causal flash attention, swapped QK^T, async dbuf staging ----
// grid: (16 qtiles, 16 h, 4 b), 256 threads = 4 waves, each wave 32 q-rows.
// LDS layout: K/V tiles [64][64] bf16 with XOR swizzle (byte ^= (row&7)<<4),
// achieved by pre-swizzling the GLOBAL source address (gload_lds dest linear).
__global__ __launch_bounds__(256) void attn_fwd(const u16* __restrict__ Qp,
                                                const u16* __restrict__ Kp,
                                                const u16* __restrict__ Vt,
                                                const float* __restrict__ Mb,
                                                u16* __restrict__ Out) {
  __shared__ __align__(16) u16 Klds[2][KVBLK * DK];
  __shared__ __align__(16) u16 Vlds[2][DK * KVBLK];
  __shared__ __align__(16) u16 Plds[4][32 * KVBLK];
  int qt = (N_ / QBLK - 1) - blockIdx.x; // heavy tiles first
  int h = blockIdx.y, b = blockIdx.z;
  int tid = threadIdx.x, w = tid >> 6, lane = tid & 63;
  int g = lane >> 4, c = lane & 15;
  int q0 = qt * QBLK;
  int wq0 = q0 + w * 32; // this wave's first q row

  const u16* kbase = Kp + (size_t)b * N_ * D_MODEL + h * DK;
  const u16* vbase = Vt + (size_t)(b * NHEAD + h) * DK * N_;
  const float* mbase = Mb + (size_t)b * N_;

  // staging geometry (per wave, 2 ops each for K and V per tile)
  int srow = (lane >> 3);              // 0..7 within the 8-row chunk
  int colb = (lane & 7) * 16;          // byte col
  int scol = (colb ^ (srow << 4)) >> 1; // pre-swizzled source col (elems)
  int r0 = w * 16, r1 = w * 16 + 8;    // this wave's rows
  u16* Kd0[2], *Kd1[2], *Vd0[2], *Vd1[2];
#pragma unroll
  for (int bb = 0; bb < 2; ++bb) {
    Kd0[bb] = &Klds[bb][r0 * DK]; Kd1[bb] = &Klds[bb][r1 * DK];
    Vd0[bb] = &Vlds[bb][r0 * DK]; Vd1[bb] = &Vlds[bb][r1 * DK];
  }

  // Q fragments (B-operand): lane holds Q[wq0+m*16+c][kh*32+g*8+e]
  s16x8 qf[2][2];
#pragma unroll
  for (int m = 0; m < 2; ++m) {
    const u16* qb2 = Qp + (size_t)(b * N_ + wq0 + m * 16 + c) * D_MODEL + h * DK;
#pragma unroll
    for (int kh = 0; kh < 2; ++kh) qf[m][kh] = *(const s16x8*)(qb2 + kh * 32 + g * 8);
  }

  const f32x4 fzero = {0.f, 0.f, 0.f, 0.f};
  f32x4 oacc[2][4];
#pragma unroll
  for (int m = 0; m < 2; ++m)
#pragma unroll
    for (int d = 0; d < 4; ++d) oacc[m][d] = fzero;
  float mr[2] = {-1e30f, -1e30f}, lr[2] = {0.f, 0.f};

  int nt = 2 * qt + 2;
  int sw = (c & 7) << 4;

  // prologue: stage tile 0 into buf 0
  {
    const u16* kp = kbase + (size_t)(0 + r0 + srow) * D_MODEL + scol;
    gload_lds16(kp, Kd0[0]);
    gload_lds16(kbase + (size_t)(r1 + srow) * D_MODEL + scol, Kd1[0]);
    gload_lds16(vbase + (size_t)(r0 + srow) * N_ + 0 + scol, Vd0[0]);
    gload_lds16(vbase + (size_t)(r1 + srow) * N_ + 0 + scol, Vd1[0]);
  }

  for (int t = 0; t < nt; ++t) {
    int kv0 = t * KVBLK;
    bool active = (kv0 <= wq0 + 31);
    // mask-bias loads BEFORE next stage (keeps counted-vmcnt valid)
    f32x4 mbv[4];
    if (active) {
#pragma unroll
      for (int n = 0; n < 4; ++n)
        mbv[n] = *(const f32x4*)&mbase[kv0 + n * 16 + g * 4];
    }
    if (t + 1 < nt) {
      int kvn = kv0 + KVBLK, bn = (t + 1) & 1;
      gload_lds16(kbase + (size_t)(kvn + r0 + srow) * D_MODEL + scol, Kd0[bn]);
      gload_lds16(kbase + (size_t)(kvn + r1 + srow) * D_MODEL + scol, Kd1[bn]);
      gload_lds16(vbase + (size_t)(r0 + srow) * N_ + kvn + scol, Vd0[bn]);
      gload_lds16(vbase + (size_t)(r1 + srow) * N_ + kvn + scol, Vd1[bn]);
      asm volatile("s_waitcnt vmcnt(4)" ::: "memory");
    } else {
      asm volatile("s_waitcnt vmcnt(0)" ::: "memory");
    }
    __syncthreads();

    if (active) {
      const u16* Kl = Klds[t & 1];
      const u16* Vl = Vlds[t & 1];
      u16* Pw = &Plds[w][0];

      // ---- S^T = K Q^T : st[m][n][r] = S[q=wq0+m*16+c][kv=kv0+n*16+g*4+r]
      f32x4 st[2][4];
#pragma unroll
      for (int n = 0; n < 4; ++n) {
        const u16* kr = &Kl[(n * 16 + c) * DK];
        s16x8 kf0 = *(const s16x8*)&kr[((g * 16) ^ sw) >> 1];
        s16x8 kf1 = *(const s16x8*)&kr[((g * 16 + 64) ^ sw) >> 1];
#pragma unroll
        for (int m = 0; m < 2; ++m) {
          f32x4 acc = __builtin_amdgcn_mfma_f32_16x16x32_bf16(kf0, qf[m][0], fzero, 0, 0, 0);
          st[m][n] = __builtin_amdgcn_mfma_f32_16x16x32_bf16(kf1, qf[m][1], acc, 0, 0, 0);
        }
      }

      // ---- scale + padding bias + causal mask, per-lane row max (16 vals)
      bool diag = (kv0 + KVBLK - 1 > wq0);
      float pmax[2];
#pragma unroll
      for (int m = 0; m < 2; ++m) {
        int qq = wq0 + m * 16 + c;
#pragma unroll
        for (int n = 0; n < 4; ++n)
#pragma unroll
          for (int r = 0; r < 4; ++r) {
            float v = fmaf(st[m][n][r], SCALE2, mbv[n][r]);
            if (diag) {
              int kv = kv0 + n * 16 + g * 4 + r;
              v = (kv > qq) ? -INFINITY : v;
            }
            st[m][n][r] = v;
          }
        float m01 = fmaxf(fmaxf(st[m][0][0], st[m][0][1]), fmaxf(st[m][0][2], st[m][0][3]));
        float m11 = fmaxf(fmaxf(st[m][1][0], st[m][1][1]), fmaxf(st[m][1][2], st[m][1][3]));
        float m21 = fmaxf(fmaxf(st[m][2][0], st[m][2][1]), fmaxf(st[m][2][2], st[m][2][3]));
        float m31 = fmaxf(fmaxf(st[m][3][0], st[m][3][1]), fmaxf(st[m][3][2], st[m][3][3]));
        float pm = fmaxf(fmaxf(m01, m11), fmaxf(m21, m31));
        pm = fmaxf(pm, __shfl_xor(pm, 16));
        pm = fmaxf(pm, __shfl_xor(pm, 32));
        pmax[m] = pm;
      }

      // ---- defer-max rescale (T13): only when max grew by > 8 (exp2 domain)
#pragma unroll
      for (int m = 0; m < 2; ++m) {
        if (__any(pmax[m] > mr[m] + 8.f)) {
          float mnew = fmaxf(mr[m], pmax[m]);
          float al = exp2f(mr[m] - mnew);
          mr[m] = mnew;
          lr[m] *= al;
          float alT[4];
#pragma unroll
          for (int r = 0; r < 4; ++r) alT[r] = __shfl(al, (g << 2) + r);
#pragma unroll
          for (int d = 0; d < 4; ++d)
#pragma unroll
            for (int r = 0; r < 4; ++r) oacc[m][d][r] *= alT[r];
        }
      }

      // ---- p = exp2(s - m), row sum, P -> LDS (b64 writes, consecutive r)
#pragma unroll
      for (int m = 0; m < 2; ++m) {
        float rs = 0.f;
#pragma unroll
        for (int n = 0; n < 4; ++n) {
#pragma unroll
          for (int r = 0; r < 4; ++r) {
            float p = exp2f(st[m][n][r] - mr[m]);
            st[m][n][r] = p;
            rs += p;
          }
          u32 lo = (u32)f2b(st[m][n][0]) | ((u32)f2b(st[m][n][1]) << 16);
          u32 hi = (u32)f2b(st[m][n][2]) | ((u32)f2b(st[m][n][3]) << 16);
          u32x2 pv = {lo, hi};
          *(u32x2*)&Pw[(m * 16 + c) * DK + (((n * 32 + g * 8) ^ sw) >> 1)] = pv;
        }
        rs += __shfl_xor(rs, 16);
        rs += __shfl_xor(rs, 32);
        lr[m] += rs;
      }
      __builtin_amdgcn_sched_barrier(0);

      // ---- O += P * V
#pragma unroll
      for (int ks = 0; ks < 2; ++ks) {
        int co = ((ks * 64 + g * 16) ^ sw) >> 1;
        s16x8 pf[2];
#pragma unroll
        for (int m = 0; m < 2; ++m)
          pf[m] = *(const s16x8*)&Pw[(m * 16 + c) * DK + co];
#pragma unroll
        for (int d = 0; d < 4; ++d) {
          s16x8 vf = *(const s16x8*)&Vl[(d * 16 + c) * DK + co];
#pragma unroll
          for (int m = 0; m < 2; ++m)
            oacc[m][d] = __builtin_amdgcn_mfma_f32_16x16x32_bf16(pf[m], vf, oacc[m][d], 0, 0, 0);
        }
      }
    }
    __syncthreads();
  }

  // ---- normalize + store bf16 [B,N,H*64]; O rows are q = wq0+m*16+g*4+r
#pragma unroll
  for (int m = 0; m < 2; ++m) {
    float lT[4];
#pragma unroll
    for (int r = 0; r < 4; ++r) lT[r] = __shfl(lr[m], (g << 2) + r);
#pragma unroll
    for (int r = 0; r < 4; ++r) {
      float inv = lT[r] > 0.f ? 1.f / lT[r] : 0.f;
#pragma unroll
      for (int d = 0; d < 4; ++d) {
        size_t idx = (size_t)(b * N_ + wq0 + m * 16 + g * 4 + r) * D_MODEL + h * DK + d * 16 + c;
        Out[idx] = f2b(oacc[m][d][r] * inv);
      }
    }
  }
}

extern "C" void kernel_launch(void* const* d_in, const int* in_sizes, int n_in,
                              void* d_out, int out_size, void* d_ws, size_t ws_size,
                              hipStream_t stream) {
  const float* q = (const float*)d_in[0];
  const float* k = (const float*)d_in[1];
  const float* v = (const float*)d_in[2];
  const int* mask = (const int*)d_in[3];
  const float* Wq = (const float*)d_in[4];
  const float* Wk = (const float*)d_in[5];
  const float* Wv = (const float*)d_in[6];
  const float* Wo = (const float*)d_in[7];
  float* out = (float*)d_out;

  char* ws = (char*)d_ws;
  const size_t SZ = (size_t)M_TOT * D_MODEL * 2; // 16 MiB per bf16 [8192,1024]
  u16* qb = (u16*)ws;
  u16* kb = (u16*)(ws + SZ);
  u16* vb = (u16*)(ws + 2 * SZ);
  u16* Qp = (u16*)(ws + 3 * SZ);
  u16* Kp = (u16*)(ws + 4 * SZ);
  u16* Wqt = (u16*)(ws + 5 * SZ);
  u16* Wkt = Wqt + 1024 * 1024;
  u16* Wvt = Wkt + 1024 * 1024;
  u16* Wot = Wvt + 1024 * 1024;
  float* Mb = (float*)(Wot + 1024 * 1024);
  // aliases (lifetime-disjoint):
  u16* attn_out = qb; // qb dead after Q GEMM
  u16* Vp = kb;       // kb dead after K GEMM
  u16* Vt = vb;       // vb dead after V GEMM

  int n4 = M_TOT * D_MODEL / 4;
  cvt_f32_bf16<<<n4 / 256, 256, 0, stream>>>(q, qb, n4);
  cvt_f32_bf16<<<n4 / 256, 256, 0, stream>>>(k, kb, n4);
  cvt_f32_bf16<<<n4 / 256, 256, 0, stream>>>(v, vb, n4);
  mask_bias<<<(B_ * N_ + 255) / 256, 256, 0, stream>>>(mask, Mb, B_ * N_);
  dim3 wg(32, 32);
  wtrans<<<wg, 256, 0, stream>>>(Wq, Wqt);
  wtrans<<<wg, 256, 0, stream>>>(Wk, Wkt);
  wtrans<<<wg, 256, 0, stream>>>(Wv, Wvt);
  wtrans<<<wg, 256, 0, stream>>>(Wo, Wot);
  dim3 gg(D_MODEL / 128, M_TOT / 128);
  gemm_bt<false><<<gg, 256, 0, stream>>>(qb, Wqt, nullptr, Qp, M_TOT, D_MODEL, D_MODEL);
  gemm_bt<false><<<gg, 256, 0, stream>>>(kb, Wkt, nullptr, Kp, M_TOT, D_MODEL, D_MODEL);
  gemm_bt<false><<<gg, 256, 0, stream>>>(vb, Wvt, nullptr, Vp, M_TOT, D_MODEL, D_MODEL);
  vtrans<<<dim3(N_ / 64, NHEAD, B_), 256, 0, stream>>>(Vp, Vt);
  attn_fwd<<<dim3(N_ / QBLK, NHEAD, B_), 256, 0, stream>>>(Qp, Kp, Vt, Mb, attn_out);
  gemm_bt<true><<<gg, 256, 0, stream>>>(attn_out, Wot, out, nullptr, M_TOT, D_MODEL, D_MODEL);
}